// Round 3
// baseline (1607.970 us; speedup 1.0000x reference)
//
#include <hip/hip_runtime.h>
#include <stdint.h>

#define LSEG 8
#define NCAND 7168
#define SLEN 256
#define MAXW 30
#define KOUT 128
#define DEMB 2304
#define DHID 150
#define PADV (SLEN + MAXW + 1) /* 287 */

// ---------------------------------------------------------------------------
// Kernel 0: transpose W1 [2304][150] -> W1T [150][2304] (coalesced writes)
// ---------------------------------------------------------------------------
__global__ __launch_bounds__(256) void k_transpose(const float* __restrict__ w1,
                                                   float* __restrict__ w1t) {
    int i = blockIdx.x * 256 + threadIdx.x;  // over 150*2304 = 345600
    if (i < DHID * DEMB) {
        int n = i / DEMB;
        int k = i - n * DEMB;
        w1t[i] = w1[k * DHID + n];
    }
}

// ---------------------------------------------------------------------------
// Kernel 1: scores[m] = W2 . relu(W1^T emb[m] + b1) + b2  for m in [0,57344)
// Block tile: 64 rows x 160 cols (150 padded), K-tile 64.
// Thread tile: 4m x 10n. LDS strides 68 floats (16B-aligned, 2-way max alias).
// ---------------------------------------------------------------------------
__global__ __launch_bounds__(256, 2) void k_scores(
    const float* __restrict__ emb, const float* __restrict__ w1t,
    const float* __restrict__ b1, const float* __restrict__ w2,
    const float* __restrict__ b2, float* __restrict__ scores) {
    __shared__ float smem[64 * 68 + 160 * 68];  // 60928 B
    float* amem = smem;            // [64][68]  a[m][k]
    float* wmem = smem + 64 * 68;  // [160][68] w[n][k]

    const int tid = threadIdx.x;
    const int tx = tid & 15;   // n-group
    const int ty = tid >> 4;   // m-group (0..15)
    const int M0 = blockIdx.x * 64;

    // zero the padded rows n=150..159 once (persist across K-tiles)
    for (int i = tid; i < 10 * 68; i += 256) wmem[150 * 68 + i] = 0.f;

    float acc[4][10];
#pragma unroll
    for (int i = 0; i < 4; ++i) {
#pragma unroll
        for (int j = 0; j < 10; ++j) acc[i][j] = 0.f;
    }

    for (int k0 = 0; k0 < DEMB; k0 += 64) {
        __syncthreads();
        // stage A: emb rows M0..M0+63, cols k0..k0+63 (coalesced float4)
#pragma unroll
        for (int r = 0; r < 4; ++r) {
            int m = ty + 16 * r;
            float4 v = *(const float4*)(emb + (size_t)(M0 + m) * DEMB + k0 + tx * 4);
            *(float4*)(amem + m * 68 + tx * 4) = v;
        }
        // stage B: W1T rows 0..149, cols k0..k0+63 -> 150*16 = 2400 float4 chunks
        for (int c = tid; c < 2400; c += 256) {
            int n = c >> 4, q = c & 15;
            float4 v = *(const float4*)(w1t + (size_t)n * DEMB + k0 + q * 4);
            *(float4*)(wmem + n * 68 + q * 4) = v;
        }
        __syncthreads();
#pragma unroll 4
        for (int kk = 0; kk < 64; kk += 4) {
            float4 av[4];
            float4 wv[10];
#pragma unroll
            for (int i = 0; i < 4; ++i)
                av[i] = *(const float4*)(amem + (ty * 4 + i) * 68 + kk);
#pragma unroll
            for (int j = 0; j < 10; ++j)
                wv[j] = *(const float4*)(wmem + (tx + 16 * j) * 68 + kk);
#pragma unroll
            for (int i = 0; i < 4; ++i) {
#pragma unroll
                for (int j = 0; j < 10; ++j) {
                    acc[i][j] += av[i].x * wv[j].x;
                    acc[i][j] += av[i].y * wv[j].y;
                    acc[i][j] += av[i].z * wv[j].z;
                    acc[i][j] += av[i].w * wv[j].w;
                }
            }
        }
    }

    // epilogue: h = relu(z + b1), partial score = sum_j h * w2
    float partial[4] = {0.f, 0.f, 0.f, 0.f};
#pragma unroll
    for (int j = 0; j < 10; ++j) {
        int n = tx + 16 * j;
        float bb = (n < DHID) ? b1[n] : 0.f;
        float ww = (n < DHID) ? w2[n] : 0.f;
#pragma unroll
        for (int i = 0; i < 4; ++i) {
            float h = acc[i][j] + bb;
            h = fmaxf(h, 0.f);
            partial[i] += h * ww;
        }
    }
    __syncthreads();
    float* red = smem;  // reuse A region: [64][17]
#pragma unroll
    for (int i = 0; i < 4; ++i) red[(ty * 4 + i) * 17 + tx] = partial[i];
    __syncthreads();
    if (tid < 64) {
        float sacc = 0.f;
#pragma unroll
        for (int t = 0; t < 16; ++t) sacc += red[tid * 17 + t];
        scores[M0 + tid] = sacc + b2[0];
    }
}

// ---------------------------------------------------------------------------
// Kernel 2: per-segment: stable sort by (-score, idx), greedy non-crossing
// selection (early exit at n==K), re-sort selected by (start,end,slot), emit.
// NOTE: indices are emitted as FLOAT values — the harness reads the whole
// d_out buffer as float32 (tuple outputs concatenated, single dtype).
// ---------------------------------------------------------------------------
__global__ __launch_bounds__(1024) void k_extract(
    const float* __restrict__ scores,
    const int* __restrict__ cs, const int* __restrict__ ce,
    float* __restrict__ out_sc, float* __restrict__ out_idx) {
    __shared__ unsigned ks[8192];        // 32 KB: sort key, later packed (s,e)
    __shared__ unsigned short id[8192];  // 16 KB: candidate index payload
    __shared__ int le[352];              // latest_end
    __shared__ int es[352];              // earliest_start
    __shared__ int sel_idx[KOUT];
    __shared__ unsigned sel_se[KOUT];
    __shared__ unsigned skey[KOUT];
    __shared__ int nshare;

    const int tid = threadIdx.x;
    const int l = blockIdx.x;
    const int base = l * NCAND;

    for (int i = tid; i < 352; i += 1024) { le[i] = -1; es[i] = PADV; }
    if (tid < KOUT) { sel_idx[tid] = 0; sel_se[tid] = 0; }

    // fill keys: ascending key == descending score, tie -> ascending idx
    for (int t = tid; t < 8192; t += 1024) {
        if (t < NCAND) {
            unsigned u = __float_as_uint(scores[base + t]);
            u = (u & 0x80000000u) ? ~u : (u | 0x80000000u);  // total-order asc
            ks[t] = ~u;                                      // descending
            id[t] = (unsigned short)t;
        } else {
            ks[t] = 0xFFFFFFFFu;
            id[t] = 0xFFFFu;
        }
    }

    // bitonic sort ascending over (ks, id) lexicographic
    for (int k = 2; k <= 8192; k <<= 1) {
        for (int j = k >> 1; j > 0; j >>= 1) {
            __syncthreads();
            for (int t = tid; t < 8192; t += 1024) {
                int p = t ^ j;
                if (p > t) {
                    unsigned ka = ks[t], kb = ks[p];
                    unsigned short ia = id[t], ib = id[p];
                    bool agtb = (ka > kb) || (ka == kb && ia > ib);
                    bool up = ((t & k) == 0);
                    if (agtb == up) {
                        ks[t] = kb; ks[p] = ka;
                        id[t] = ib; id[p] = ia;
                    }
                }
            }
        }
    }
    __syncthreads();

    // repack ks[t] = start | (end<<16), in sorted order (keeps greedy LDS-only)
    for (int t = tid; t < NCAND; t += 1024) {
        int i0 = id[t];
        ks[t] = (unsigned)cs[base + i0] | ((unsigned)ce[base + i0] << 16);
    }
    __syncthreads();

    // greedy scan, wave 0 only; crossing check over 31 lanes
    if (tid < 64) {
        volatile unsigned* ksv = ks;
        volatile int* lev = le;
        volatile int* esv = es;
        const int lane = tid;
        int n = 0;
        for (int t = 0; t < NCAND; ++t) {
            if (n >= KOUT) break;
            unsigned se = ksv[t];
            int s = (int)(se & 0xFFFFu);
            int e = (int)(se >> 16);
            int w = e - s;
            int ro = (lane <= MAXW) ? lane : 0;
            int lv = lev[s + ro];
            int ev = esv[s + ro];
            bool c1 = (lane >= 1) && (lane <= w) && (lv > e);   // j in (s,e]
            bool c2 = (lane < w) && (ev < s);                   // j in [s,e)
            bool crossing = (__ballot(c1 || c2) != 0ull);
            if (!crossing) {
                if (lane == 0) {
                    sel_idx[n] = (int)id[t];
                    sel_se[n] = se;
                    if (e > lev[s]) lev[s] = e;
                    if (s < esv[e]) esv[e] = s;
                }
                n++;
            }
            __threadfence_block();
        }
        if (lane == 0) nshare = n;
    }
    __syncthreads();

    const int nsel = nshare;
    // build final sort keys: (start*287+end)<<7 | slot (stable on ties)
    if (tid < KOUT) {
        if (tid < nsel) {
            unsigned se = sel_se[tid];
            int s = (int)(se & 0xFFFFu);
            int e = (int)(se >> 16);
            skey[tid] = ((unsigned)(s * PADV + e) << 7) | (unsigned)tid;
        } else {
            skey[tid] = 0x7F000000u | (unsigned)tid;
        }
    }
    // bitonic 128 ascending
    for (int k = 2; k <= KOUT; k <<= 1) {
        for (int j = k >> 1; j > 0; j >>= 1) {
            __syncthreads();
            if (tid < KOUT) {
                int t = tid, p = t ^ j;
                if (p > t) {
                    unsigned a = skey[t], b = skey[p];
                    bool up = ((t & k) == 0);
                    if ((a > b) == up) { skey[t] = b; skey[p] = a; }
                }
            }
        }
    }
    __syncthreads();
    if (tid < KOUT) {
        int oslot = (int)(skey[tid] & 127u);
        int slot0 = (int)(skey[0] & 127u);
        int oi = (tid < nsel) ? sel_idx[oslot] : sel_idx[slot0];
        out_idx[l * KOUT + tid] = (float)oi;   // harness reads d_out as float32
        out_sc[l * KOUT + tid] = scores[base + oi];
    }
}

// ---------------------------------------------------------------------------
extern "C" void kernel_launch(void* const* d_in, const int* in_sizes, int n_in,
                              void* d_out, int out_size, void* d_ws, size_t ws_size,
                              hipStream_t stream) {
    const float* emb = (const float*)d_in[0];
    const float* w1  = (const float*)d_in[1];
    const float* b1  = (const float*)d_in[2];
    const float* w2  = (const float*)d_in[3];
    const float* b2  = (const float*)d_in[4];
    const int*   cs  = (const int*)d_in[5];
    const int*   ce  = (const int*)d_in[6];

    float* ws_scores = (float*)d_ws;                    // 57344 floats (229 KB)
    float* ws_w1t    = (float*)((char*)d_ws + 262144);  // 150*2304 floats (1.35 MB)

    k_transpose<<<dim3(1350), dim3(256), 0, stream>>>(w1, ws_w1t);
    k_scores<<<dim3((LSEG * NCAND) / 64), dim3(256), 0, stream>>>(
        emb, ws_w1t, b1, w2, b2, ws_scores);
    k_extract<<<dim3(LSEG), dim3(1024), 0, stream>>>(
        ws_scores, cs, ce, (float*)d_out, (float*)d_out + LSEG * KOUT);
}